// Round 7
// baseline (265.362 us; speedup 1.0000x reference)
//
#include <hip/hip_runtime.h>
#include <hip/hip_bf16.h>

// B=4, S=2048, E=1024, H=16, D=64, WIN=512.
// out = ( swa_alibi( split_heads(x @ w_in^T) ) merged ) @ w_out^T

typedef __bf16 bf16x8 __attribute__((ext_vector_type(8)));
typedef __bf16 bf16x4 __attribute__((ext_vector_type(4)));
typedef short short4v __attribute__((ext_vector_type(4)));
typedef float f32x4 __attribute__((ext_vector_type(4)));

__device__ __forceinline__ f32x4 mfma16(bf16x8 a, bf16x8 b, f32x4 c) {
    return __builtin_amdgcn_mfma_f32_16x16x32_bf16(a, b, c, 0, 0, 0);
}

// K=16 bf16 MFMA: B-fragment (lane: n=l16, k=q4*4+j) matches the S^T softmax
// register layout exactly -> P never leaves registers.
__device__ __forceinline__ f32x4 mfma16k16(bf16x4 a, bf16x4 b, f32x4 c) {
#if __has_builtin(__builtin_amdgcn_mfma_f32_16x16x16bf16_1k)
    return __builtin_amdgcn_mfma_f32_16x16x16bf16_1k(
        __builtin_bit_cast(short4v, a), __builtin_bit_cast(short4v, b), c, 0, 0, 0);
#elif __has_builtin(__builtin_amdgcn_mfma_f32_16x16x16_bf16)
    return __builtin_amdgcn_mfma_f32_16x16x16_bf16(a, b, c, 0, 0, 0);
#else
    asm("v_mfma_f32_16x16x16_bf16 %0, %1, %2, %0" : "+v"(c) : "v"(a), "v"(b));
    return c;
#endif
}

__device__ __forceinline__ void gload_lds16(const void* g, void* l) {
    __builtin_amdgcn_global_load_lds(
        (const __attribute__((address_space(1))) unsigned int*)(unsigned long long)g,
        (__attribute__((address_space(3))) unsigned int*)(unsigned int)(unsigned long long)l,
        16, 0, 0);
}

__device__ __forceinline__ unsigned pkbf(float a, float b) {
    unsigned short ua = __builtin_bit_cast(unsigned short, (__bf16)a);
    unsigned short ub = __builtin_bit_cast(unsigned short, (__bf16)b);
    return (unsigned)ua | ((unsigned)ub << 16);
}

__global__ void init_flag(int* flag) { *flag = 0; }

// f32 data read as bf16 halfwords shows huge exponents (p~0.45 per halfword).
__global__ void detect_f32(const unsigned short* __restrict__ w, int n, int* flag) {
    int i = blockIdx.x * blockDim.x + threadIdx.x;
    int hit = 0;
    for (; i < n; i += gridDim.x * blockDim.x) {
        int e = (w[i] >> 7) & 0xFF;
        if (e >= 0x8D) hit = 1;
    }
    unsigned long long m = __ballot(hit);
    if (m != 0 && (threadIdx.x & 63) == 0) atomicOr(flag, 1);
}

// Single launch: converts all three inputs f32->bf16 iff flag set; else no-op.
// float4 loads + packed uint2 stores (G13 — memory-bound; proven R6).
__global__ void cvt_all(const void* __restrict__ x, const void* __restrict__ wi,
                        const void* __restrict__ wo, __bf16* __restrict__ xb,
                        __bf16* __restrict__ wib, __bf16* __restrict__ wob,
                        const int* __restrict__ flag) {
    if (*flag == 0) return;
    const int XN = 8192 * 1024 / 4, WI = 3072 * 1024 / 4, WO = 1024 * 1024 / 4;
    const int stride = gridDim.x * blockDim.x;
    const int i0 = blockIdx.x * blockDim.x + threadIdx.x;
    const float4* xs = (const float4*)x;
    const float4* ws1 = (const float4*)wi;
    const float4* ws2 = (const float4*)wo;
    for (int j = i0; j < XN; j += stride) {
        float4 v = xs[j];
        uint2 pk; pk.x = pkbf(v.x, v.y); pk.y = pkbf(v.z, v.w);
        *(uint2*)&xb[(size_t)j * 4] = pk;
    }
    for (int j = i0; j < WI; j += stride) {
        float4 v = ws1[j];
        uint2 pk; pk.x = pkbf(v.x, v.y); pk.y = pkbf(v.z, v.w);
        *(uint2*)&wib[(size_t)j * 4] = pk;
    }
    for (int j = i0; j < WO; j += stride) {
        float4 v = ws2[j];
        uint2 pk; pk.x = pkbf(v.x, v.y); pk.y = pkbf(v.z, v.w);
        *(uint2*)&wob[(size_t)j * 4] = pk;
    }
}

// C[M,N] = A[M,K] @ Bt[N,K]^T. 128x128 tile, BK=64, global_load_lds staging
// with XOR-chunk lane mapping (pre-swizzled global source, linear LDS dest).
// Bijective XCD swizzle on the block mapping (proven ~10us, R4->R5 non-attn).
__global__ __launch_bounds__(256, 3) void gemm_bt(
        const void* __restrict__ Araw, const __bf16* __restrict__ Acvt,
        const void* __restrict__ Braw, const __bf16* __restrict__ Bcvt,
        __bf16* __restrict__ Cb, float* __restrict__ Cf,
        const int* __restrict__ flagp, int M, int N, int K) {
    __shared__ __align__(16) __bf16 As[128 * 64];
    __shared__ __align__(16) __bf16 Bs[128 * 64];

    const int t = threadIdx.x;
    const int lane = t & 63;
    const int w = t >> 6;
    const int wr = w >> 1, wc = w & 1;
    const int q4 = lane >> 4, l16 = lane & 15;

    const int nwg = gridDim.x * gridDim.y;
    const int lin = blockIdx.y * gridDim.x + blockIdx.x;
    const int slin = (lin & 7) * (nwg >> 3) + (lin >> 3);
    const int bx = slin % gridDim.x;
    const int by = slin / gridDim.x;
    const int m0 = by * 128, n0 = bx * 128;

    const bool isf32 = (*flagp != 0);
    const __bf16* A = isf32 ? Acvt : (const __bf16*)Araw;
    const __bf16* Bt = isf32 ? Bcvt : (const __bf16*)Braw;

    f32x4 acc[4][4] = {};

    const int lr = lane >> 3;
    const int lc = (lane & 7) ^ lr;

    for (int k0 = 0; k0 < K; k0 += 64) {
#pragma unroll
        for (int p = 0; p < 4; ++p) {
            int r0 = w * 32 + p * 8;
            gload_lds16(&A[(size_t)(m0 + r0 + lr) * K + k0 + lc * 8], &As[r0 * 64]);
            gload_lds16(&Bt[(size_t)(n0 + r0 + lr) * K + k0 + lc * 8], &Bs[r0 * 64]);
        }
        __syncthreads();

#pragma unroll
        for (int kt = 0; kt < 2; ++kt) {
            bf16x8 af[4], bfr[4];
#pragma unroll
            for (int mt = 0; mt < 4; ++mt) {
                int row = wr * 64 + mt * 16 + l16;
                af[mt] = *(const bf16x8*)&As[row * 64 + (((kt * 4 + q4) ^ (row & 7)) << 3)];
            }
#pragma unroll
            for (int nt = 0; nt < 4; ++nt) {
                int row = wc * 64 + nt * 16 + l16;
                bfr[nt] = *(const bf16x8*)&Bs[row * 64 + (((kt * 4 + q4) ^ (row & 7)) << 3)];
            }
#pragma unroll
            for (int mt = 0; mt < 4; ++mt)
#pragma unroll
                for (int nt = 0; nt < 4; ++nt)
                    acc[mt][nt] = mfma16(af[mt], bfr[nt], acc[mt][nt]);
        }
        __syncthreads();
    }

    // C/D layout: col=lane&15, row=(lane>>4)*4+reg
#pragma unroll
    for (int mt = 0; mt < 4; ++mt)
#pragma unroll
        for (int nt = 0; nt < 4; ++nt) {
            int col = n0 + wc * 64 + nt * 16 + l16;
#pragma unroll
            for (int r = 0; r < 4; ++r) {
                int row = m0 + wr * 64 + mt * 16 + q4 * 4 + r;
                if (Cf && isf32)
                    Cf[(size_t)row * N + col] = acc[mt][nt][r];
                else
                    Cb[(size_t)row * N + col] = (__bf16)acc[mt][nt][r];
            }
        }
}

// Sliding-window causal attention + ALiBi, flash-style, S^T orientation.
// R7: 512-thread blocks (8 waves) over a 256-query strip sharing the SAME
// K/V LDS tiles — LDS/block unchanged (67.6 KB, 2 blocks/CU) but waves/CU
// 8 -> 16 (VGPR must stay <=128 for 4 waves/SIMD; live set ~112 and vpre
// halves). K-tiles per (h,b) drop 70 -> 42 (each serves 2x queries).
// Grid 512 = exactly 2 blocks/CU, decode pairs (qt a, a+4) per CU.
// Design rules from R1-R5 (all measured):
//  - ONE barrier per 128-key tile; K dbuf + V dbuf (R5: extra barrier for
//    LDS savings cost +10us).
//  - Generous launch bounds: tight caps produced 85-230 MB spill (R1/R2).
//  - K via global_load_lds DMA (R4: +19us vs direct-from-global).
// Per-wave inner loop unchanged: register-resident P (K=16 PV MFMAs),
// defer-max, interior-mask skip, swizzled Ks/Vts.
__global__ __launch_bounds__(512, 2) void attn(
        const __bf16* __restrict__ qkv, __bf16* __restrict__ o) {
    // Ks[2]:  128 keys x 64 d, pitch 64, chunk-swizzled (DMA)  [0, 32768)
    // Vts[2]: 64 d x 128 keys, pitch 136, chunk-swizzled       [32768, 67584)
    // Ot: epilogue transpose buffer (256 rows x 64 = 32768 B), aliases Ks
    __shared__ __align__(16) char smem[2 * 16384 + 2 * 17408];
    __bf16* Ks  = (__bf16*)smem;
    __bf16* Vts = (__bf16*)(smem + 32768);
    __bf16* Ot  = (__bf16*)smem;

    // decode: CU c gets blocks {c, c+256} -> qt pairs (a, a+4), work 8..12
    const int L = blockIdx.x;
    const int u = L & 255, v = L >> 8;
    const int qt = v * 4 + (u & 3);   // [0,8) — 256-query strips
    const int h  = (u >> 2) & 15;
    const int b  = u >> 6;

    const int t = threadIdx.x;
    const int lane = t & 63, w = t >> 6;          // w in [0,8)
    const int q4 = lane >> 4, l16 = lane & 15;
    const int q0 = qt * 256, qw0 = q0 + w * 32;

    const float L2E = 1.4426950408889634f;
    const float slope2 = exp2f(-(float)(h + 1) * 0.5f) * L2E;  // alibi slope * log2e
    const float scale2 = L2E * 0.125f;                         // log2e / sqrt(64)

    // V staging coords: thread handles key row (p*64+srow), d-chunk scb
    const int srow = t >> 3, scb = t & 7;         // srow in [0,64)
    // K DMA coords: lane covers row-in-8 lr, swizzled global chunk lc
    const int lr = lane >> 3;
    const int lc = (lane & 7) ^ lr;

    // Q as B-operand (lane l16 = query, k = d), straight b128 from global
    bf16x8 qf[2][2];
    const size_t qbase = ((size_t)b * 2048 + q0) * 3072 + (size_t)h * 64;
#pragma unroll
    for (int nt = 0; nt < 2; ++nt)
#pragma unroll
        for (int kt = 0; kt < 2; ++kt)
            qf[nt][kt] = *(const bf16x8*)&qkv[qbase +
                (size_t)(w * 32 + nt * 16 + l16) * 3072 + kt * 32 + q4 * 8];

    f32x4 O[4][2] = {};  // O^T: [d-tile][q-tile], col l16=q, row q4*4+r=d
    float mrow[2] = {-1e30f, -1e30f}, lrow[2] = {0.0f, 0.0f};

    // key-tile range for the 256-query strip: [qt*256-512, qt*256+255]
    const int ktile0 = (qt >= 2) ? (qt * 2 - 4) : 0;
    const int nkt = qt * 2 + 2 - ktile0;          // qt0:2, qt1:4, else 6
    const size_t bh = (size_t)b * 2048 * 3072 + (size_t)h * 64;

    uint4 vpre[2];

    // prologue: DMA K tile 0 (8 waves x 16 rows), load + commit V tile 0
    {
        const size_t kb = bh + (size_t)(ktile0 * 128) * 3072 + 1024;
#pragma unroll
        for (int p = 0; p < 2; ++p) {
            int r0 = w * 16 + p * 8;
            gload_lds16(&qkv[kb + (size_t)(r0 + lr) * 3072 + lc * 8], &Ks[r0 * 64]);
        }
#pragma unroll
        for (int p = 0; p < 2; ++p)
            vpre[p] = *(const uint4*)&qkv[kb + 1024 + (size_t)(p * 64 + srow) * 3072 + scb * 8];
#pragma unroll
        for (int p = 0; p < 2; ++p) {
            const __bf16* ve = (const __bf16*)&vpre[p];
            int R = p * 8 + (srow >> 3);
#pragma unroll
            for (int j = 0; j < 8; ++j)
                Vts[(scb * 8 + j) * 136 + ((R ^ scb) << 3) + (srow & 7)] = ve[j];
        }
    }
    __syncthreads();  // drains K DMA (vmcnt) + V commit visible

    for (int ki = 0; ki < nkt; ++ki) {
        const int k0 = (ktile0 + ki) * 128;
        const __bf16* Kb = Ks + (ki & 1) * 8192;
        const __bf16* Vb = Vts + (ki & 1) * 8704;
        if (ki + 1 < nkt) {  // issue next tile's K DMA + V reg loads (no wait)
            const size_t kb = bh + (size_t)(k0 + 128) * 3072 + 1024;
            __bf16* Kn = Ks + ((ki + 1) & 1) * 8192;
#pragma unroll
            for (int p = 0; p < 2; ++p) {
                int r0 = w * 16 + p * 8;
                gload_lds16(&qkv[kb + (size_t)(r0 + lr) * 3072 + lc * 8], &Kn[r0 * 64]);
            }
#pragma unroll
            for (int p = 0; p < 2; ++p)
                vpre[p] = *(const uint4*)&qkv[kb + 1024 + (size_t)(p * 64 + srow) * 3072 + scb * 8];
        }

#pragma unroll 1
        for (int hh = 0; hh < 2; ++hh) {
            const int ks0 = k0 + hh * 64;
            if (qw0 + 31 < ks0 || qw0 - 512 > ks0 + 63) continue;  // wave-uniform skip
            // all (q,k) pairs of this wave-subtile inside the window?
            const bool interior = (qw0 - ks0 >= 63) && (qw0 - ks0 <= 481);

            // S^T = K·Q^T over this 64-key subtile, K from swizzled LDS.
            f32x4 sc[2][4] = {};
#pragma unroll
            for (int mt = 0; mt < 4; ++mt) {
                int krow = hh * 64 + mt * 16 + l16;
                bf16x8 ak0 = *(const bf16x8*)&Kb[krow * 64 + ((q4 ^ (l16 & 7)) << 3)];
                bf16x8 ak1 = *(const bf16x8*)&Kb[krow * 64 + (((4 + q4) ^ (l16 & 7)) << 3)];
                __builtin_amdgcn_s_setprio(1);
                sc[0][mt] = mfma16(ak0, qf[0][0], sc[0][mt]);
                sc[0][mt] = mfma16(ak1, qf[0][1], sc[0][mt]);
                sc[1][mt] = mfma16(ak0, qf[1][0], sc[1][mt]);
                sc[1][mt] = mfma16(ak1, qf[1][1], sc[1][mt]);
                __builtin_amdgcn_s_setprio(0);
            }

            uint2 pb[2][4];  // P fragments, bf16x4 per (q-tile, 16-key subtile)

#pragma unroll
            for (int nt = 0; nt < 2; ++nt) {
                // mask + bias + max (query = l16, keys = mt*16 + q4*4 + r)
                const int qi = qw0 + nt * 16 + l16;
                const int db = qi - ks0 - q4 * 4;
                float tmx = -1e30f;
                if (interior) {
                    const float fb = slope2 * (float)db;
#pragma unroll
                    for (int mt = 0; mt < 4; ++mt) {
                        float bm = fb - (float)(16 * mt) * slope2;
#pragma unroll
                        for (int r = 0; r < 4; ++r) {
                            float v2 = fmaf(sc[nt][mt][r], scale2, bm - (float)r * slope2);
                            sc[nt][mt][r] = v2;
                            tmx = fmaxf(tmx, v2);
                        }
                    }
                } else {
#pragma unroll
                    for (int mt = 0; mt < 4; ++mt)
#pragma unroll
                        for (int r = 0; r < 4; ++r) {
                            int delta = db - mt * 16 - r;
                            float v2 = sc[nt][mt][r] * scale2 + slope2 * (float)delta;
                            v2 = ((unsigned)delta <= 512u) ? v2 : -1e30f;
                            sc[nt][mt][r] = v2;
                            tmx = fmaxf(tmx, v2);
                        }
                }
                tmx = fmaxf(tmx, __shfl_xor(tmx, 16));
                tmx = fmaxf(tmx, __shfl_xor(tmx, 32));

                // defer-max: rescale only if some query's max grew
                if (__any(tmx > mrow[nt])) {
                    float mnew = fmaxf(mrow[nt], tmx);
                    float al = exp2f(mrow[nt] - mnew);
                    mrow[nt] = mnew;
                    lrow[nt] *= al;
#pragma unroll
                    for (int mtd = 0; mtd < 4; ++mtd)
                        O[mtd][nt] *= al;
                }

                // P = exp2(S - m), packed to bf16x4 in-register + row-sum
                float rs = 0.0f;
#pragma unroll
                for (int mt = 0; mt < 4; ++mt) {
                    float p0 = exp2f(sc[nt][mt][0] - mrow[nt]);
                    float p1 = exp2f(sc[nt][mt][1] - mrow[nt]);
                    float p2 = exp2f(sc[nt][mt][2] - mrow[nt]);
                    float p3 = exp2f(sc[nt][mt][3] - mrow[nt]);
                    rs += (p0 + p1) + (p2 + p3);
                    uint2 pk;
                    pk.x = pkbf(p0, p1);
                    pk.y = pkbf(p2, p3);
                    pb[nt][mt] = pk;
                }
                rs += __shfl_xor(rs, 16);
                rs += __shfl_xor(rs, 32);
                lrow[nt] += rs;
            }

            // PV: A = V^T (b64 from swizzled Vts), B = P fragments (registers).
            // K=16 per MFMA: k = q4*4+j = exactly the softmax key layout.
            const int dsw = l16 >> 3;
#pragma unroll
            for (int mtB = 0; mtB < 4; ++mtB) {
                bf16x4 b0 = __builtin_bit_cast(bf16x4, pb[0][mtB]);
                bf16x4 b1 = __builtin_bit_cast(bf16x4, pb[1][mtB]);
                const int kc0 = hh * 8 + mtB * 2 + (q4 >> 1);
#pragma unroll
                for (int mtd = 0; mtd < 4; ++mtd) {
                    int kc = kc0 ^ ((mtd * 2 + dsw) & 7);
                    bf16x4 av = *(const bf16x4*)&Vb[(mtd * 16 + l16) * 136 +
                                                    (kc << 3) + (q4 & 1) * 4];
                    __builtin_amdgcn_s_setprio(1);
                    O[mtd][0] = mfma16k16(av, b0, O[mtd][0]);
                    O[mtd][1] = mfma16k16(av, b1, O[mtd][1]);
                    __builtin_amdgcn_s_setprio(0);
                }
            }
        }

        if (ki + 1 < nkt) {  // commit next V tile into the other buffer
            __bf16* Vn = Vts + ((ki + 1) & 1) * 8704;
#pragma unroll
            for (int p = 0; p < 2; ++p) {
                const __bf16* ve = (const __bf16*)&vpre[p];
                int R = p * 8 + (srow >> 3);
#pragma unroll
                for (int j = 0; j < 8; ++j)
                    Vn[(scb * 8 + j) * 136 + ((R ^ scb) << 3) + (srow & 7)] = ve[j];
            }
        }
        __syncthreads();  // readers done + K DMA drained + V commit visible
    }

    // epilogue: normalize, transpose O^T -> O via swizzled Ot (aliases Ks;
    // all accesses stay within this wave's 32-query strip -> no barrier needed)
#pragma unroll
    for (int nt = 0; nt < 2; ++nt) {
        float inv = (lrow[nt] > 0.0f) ? 1.0f / lrow[nt] : 0.0f;
        int qrow = w * 32 + nt * 16 + l16;
#pragma unroll
        for (int mtd = 0; mtd < 4; ++mtd) {
            int chunk = (mtd * 2 + (q4 >> 1)) ^ (l16 & 7);
            uint2 pk;
            pk.x = pkbf(O[mtd][nt][0] * inv, O[mtd][nt][1] * inv);
            pk.y = pkbf(O[mtd][nt][2] * inv, O[mtd][nt][3] * inv);
            *(uint2*)&Ot[qrow * 64 + (chunk << 3) + (q4 & 1) * 4] = pk;
        }
    }
    const size_t obase = ((size_t)b * 2048 + q0) * 1024 + (size_t)h * 64;
#pragma unroll
    for (int i = 0; i < 4; ++i) {
        int u2 = i * 64 + lane;
        int row = u2 >> 3, ch = u2 & 7;
        int q = w * 32 + row;
        *(uint4*)&o[obase + (size_t)q * 1024 + ch * 8] =
            *(const uint4*)&Ot[q * 64 + ((ch ^ (row & 7)) << 3)];
    }
}

extern "C" void kernel_launch(void* const* d_in, const int* in_sizes, int n_in,
                              void* d_out, int out_size, void* d_ws, size_t ws_size,
                              hipStream_t stream) {
    char* ws = (char*)d_ws;
    int* flag = (int*)ws;
    size_t off = 256;
    __bf16* xb  = (__bf16*)(ws + off); off += (size_t)8192 * 1024 * 2;
    __bf16* wib = (__bf16*)(ws + off); off += (size_t)3072 * 1024 * 2;
    __bf16* wob = (__bf16*)(ws + off); off += (size_t)1024 * 1024 * 2;
    __bf16* qkv = (__bf16*)(ws + off); off += (size_t)8192 * 3072 * 2;
    __bf16* o   = (__bf16*)(ws + off);

    init_flag<<<1, 1, 0, stream>>>(flag);
    int nscan = in_sizes[2] < 65536 ? in_sizes[2] : 65536;
    detect_f32<<<16, 256, 0, stream>>>((const unsigned short*)d_in[2], nscan, flag);
    cvt_all<<<1024, 256, 0, stream>>>(d_in[0], d_in[1], d_in[2], xb, wib, wob, flag);

    // qkv = x @ w_in^T
    gemm_bt<<<dim3(24, 64), 256, 0, stream>>>(d_in[0], xb, d_in[1], wib,
                                              qkv, nullptr, flag, 8192, 3072, 1024);
    // attention (512 blocks x 512 threads, 256-query strips)
    attn<<<dim3(512), 512, 0, stream>>>(qkv, o);
    // out = o @ w_out^T (output dtype per flag)
    gemm_bt<<<dim3(8, 64), 256, 0, stream>>>(o, o, d_in[2], wob,
                                             (__bf16*)d_out, (float*)d_out, flag,
                                             8192, 1024, 1024);
}

// Round 8
// 241.786 us; speedup vs baseline: 1.0975x; 1.0975x over previous
//
#include <hip/hip_runtime.h>
#include <hip/hip_bf16.h>

// B=4, S=2048, E=1024, H=16, D=64, WIN=512.
// out = ( swa_alibi( split_heads(x @ w_in^T) ) merged ) @ w_out^T

typedef __bf16 bf16x8 __attribute__((ext_vector_type(8)));
typedef __bf16 bf16x4 __attribute__((ext_vector_type(4)));
typedef short short4v __attribute__((ext_vector_type(4)));
typedef float f32x4 __attribute__((ext_vector_type(4)));

__device__ __forceinline__ f32x4 mfma16(bf16x8 a, bf16x8 b, f32x4 c) {
    return __builtin_amdgcn_mfma_f32_16x16x32_bf16(a, b, c, 0, 0, 0);
}

// K=16 bf16 MFMA: B-fragment (lane: n=l16, k=q4*4+j) matches the S^T softmax
// register layout exactly -> P never leaves registers.
__device__ __forceinline__ f32x4 mfma16k16(bf16x4 a, bf16x4 b, f32x4 c) {
#if __has_builtin(__builtin_amdgcn_mfma_f32_16x16x16bf16_1k)
    return __builtin_amdgcn_mfma_f32_16x16x16bf16_1k(
        __builtin_bit_cast(short4v, a), __builtin_bit_cast(short4v, b), c, 0, 0, 0);
#elif __has_builtin(__builtin_amdgcn_mfma_f32_16x16x16_bf16)
    return __builtin_amdgcn_mfma_f32_16x16x16_bf16(a, b, c, 0, 0, 0);
#else
    asm("v_mfma_f32_16x16x16_bf16 %0, %1, %2, %0" : "+v"(c) : "v"(a), "v"(b));
    return c;
#endif
}

__device__ __forceinline__ void gload_lds16(const void* g, void* l) {
    __builtin_amdgcn_global_load_lds(
        (const __attribute__((address_space(1))) unsigned int*)(unsigned long long)g,
        (__attribute__((address_space(3))) unsigned int*)(unsigned int)(unsigned long long)l,
        16, 0, 0);
}

__device__ __forceinline__ unsigned pkbf(float a, float b) {
    unsigned short ua = __builtin_bit_cast(unsigned short, (__bf16)a);
    unsigned short ub = __builtin_bit_cast(unsigned short, (__bf16)b);
    return (unsigned)ua | ((unsigned)ub << 16);
}

__global__ void init_flag(int* flag) { *flag = 0; }

// f32 data read as bf16 halfwords shows huge exponents (p~0.45 per halfword).
__global__ void detect_f32(const unsigned short* __restrict__ w, int n, int* flag) {
    int i = blockIdx.x * blockDim.x + threadIdx.x;
    int hit = 0;
    for (; i < n; i += gridDim.x * blockDim.x) {
        int e = (w[i] >> 7) & 0xFF;
        if (e >= 0x8D) hit = 1;
    }
    unsigned long long m = __ballot(hit);
    if (m != 0 && (threadIdx.x & 63) == 0) atomicOr(flag, 1);
}

// Single launch: converts all three inputs f32->bf16 iff flag set; else no-op.
// float4 loads + packed uint2 stores (G13 — memory-bound; proven R6).
__global__ void cvt_all(const void* __restrict__ x, const void* __restrict__ wi,
                        const void* __restrict__ wo, __bf16* __restrict__ xb,
                        __bf16* __restrict__ wib, __bf16* __restrict__ wob,
                        const int* __restrict__ flag) {
    if (*flag == 0) return;
    const int XN = 8192 * 1024 / 4, WI = 3072 * 1024 / 4, WO = 1024 * 1024 / 4;
    const int stride = gridDim.x * blockDim.x;
    const int i0 = blockIdx.x * blockDim.x + threadIdx.x;
    const float4* xs = (const float4*)x;
    const float4* ws1 = (const float4*)wi;
    const float4* ws2 = (const float4*)wo;
    for (int j = i0; j < XN; j += stride) {
        float4 v = xs[j];
        uint2 pk; pk.x = pkbf(v.x, v.y); pk.y = pkbf(v.z, v.w);
        *(uint2*)&xb[(size_t)j * 4] = pk;
    }
    for (int j = i0; j < WI; j += stride) {
        float4 v = ws1[j];
        uint2 pk; pk.x = pkbf(v.x, v.y); pk.y = pkbf(v.z, v.w);
        *(uint2*)&wib[(size_t)j * 4] = pk;
    }
    for (int j = i0; j < WO; j += stride) {
        float4 v = ws2[j];
        uint2 pk; pk.x = pkbf(v.x, v.y); pk.y = pkbf(v.z, v.w);
        *(uint2*)&wob[(size_t)j * 4] = pk;
    }
}

// C[M,N] = A[M,K] @ Bt[N,K]^T. 128x128 tile, BK=64, global_load_lds staging
// with XOR-chunk lane mapping (pre-swizzled global source, linear LDS dest).
// Bijective XCD swizzle on the block mapping (proven ~10us, R4->R5 non-attn).
__global__ __launch_bounds__(256, 3) void gemm_bt(
        const void* __restrict__ Araw, const __bf16* __restrict__ Acvt,
        const void* __restrict__ Braw, const __bf16* __restrict__ Bcvt,
        __bf16* __restrict__ Cb, float* __restrict__ Cf,
        const int* __restrict__ flagp, int M, int N, int K) {
    __shared__ __align__(16) __bf16 As[128 * 64];
    __shared__ __align__(16) __bf16 Bs[128 * 64];

    const int t = threadIdx.x;
    const int lane = t & 63;
    const int w = t >> 6;
    const int wr = w >> 1, wc = w & 1;
    const int q4 = lane >> 4, l16 = lane & 15;

    const int nwg = gridDim.x * gridDim.y;
    const int lin = blockIdx.y * gridDim.x + blockIdx.x;
    const int slin = (lin & 7) * (nwg >> 3) + (lin >> 3);
    const int bx = slin % gridDim.x;
    const int by = slin / gridDim.x;
    const int m0 = by * 128, n0 = bx * 128;

    const bool isf32 = (*flagp != 0);
    const __bf16* A = isf32 ? Acvt : (const __bf16*)Araw;
    const __bf16* Bt = isf32 ? Bcvt : (const __bf16*)Braw;

    f32x4 acc[4][4] = {};

    const int lr = lane >> 3;
    const int lc = (lane & 7) ^ lr;

    for (int k0 = 0; k0 < K; k0 += 64) {
#pragma unroll
        for (int p = 0; p < 4; ++p) {
            int r0 = w * 32 + p * 8;
            gload_lds16(&A[(size_t)(m0 + r0 + lr) * K + k0 + lc * 8], &As[r0 * 64]);
            gload_lds16(&Bt[(size_t)(n0 + r0 + lr) * K + k0 + lc * 8], &Bs[r0 * 64]);
        }
        __syncthreads();

#pragma unroll
        for (int kt = 0; kt < 2; ++kt) {
            bf16x8 af[4], bfr[4];
#pragma unroll
            for (int mt = 0; mt < 4; ++mt) {
                int row = wr * 64 + mt * 16 + l16;
                af[mt] = *(const bf16x8*)&As[row * 64 + (((kt * 4 + q4) ^ (row & 7)) << 3)];
            }
#pragma unroll
            for (int nt = 0; nt < 4; ++nt) {
                int row = wc * 64 + nt * 16 + l16;
                bfr[nt] = *(const bf16x8*)&Bs[row * 64 + (((kt * 4 + q4) ^ (row & 7)) << 3)];
            }
#pragma unroll
            for (int mt = 0; mt < 4; ++mt)
#pragma unroll
                for (int nt = 0; nt < 4; ++nt)
                    acc[mt][nt] = mfma16(af[mt], bfr[nt], acc[mt][nt]);
        }
        __syncthreads();
    }

    // C/D layout: col=lane&15, row=(lane>>4)*4+reg
#pragma unroll
    for (int mt = 0; mt < 4; ++mt)
#pragma unroll
        for (int nt = 0; nt < 4; ++nt) {
            int col = n0 + wc * 64 + nt * 16 + l16;
#pragma unroll
            for (int r = 0; r < 4; ++r) {
                int row = m0 + wr * 64 + mt * 16 + q4 * 4 + r;
                if (Cf && isf32)
                    Cf[(size_t)row * N + col] = acc[mt][nt][r];
                else
                    Cb[(size_t)row * N + col] = (__bf16)acc[mt][nt][r];
            }
        }
}

// Sliding-window causal attention + ALiBi, flash-style, S^T orientation.
// Internals = EXACT R4/R6 configuration (best measured attn: 76.4-76.5us,
// MfmaUtil 12.9, VALU 43.9, VGPR 112, zero spill).
// Occupancy-lever history (all measured):
//  - R5 (K dbuf + V single, 3 blocks/CU, +1 barrier/tile): +10us. Barriers
//    beat LDS residency.
//  - R7 (512-thr blocks, 2x waves/CU nominal): +11us. 8-wave barrier skew +
//    lower wave-active fraction beat TLP; time-avg occupancy DIDN'T rise.
//  - (256,3)/(256,4) launch bounds: 85-230 MB spill (R1/R2). Keep (256,2).
// R8 lever: DISPATCH ORDER ONLY. Work per block varies 1-5 key-tiles
// (qt 0..3 -> 1..4 tiles, qt>=4 -> 5). Measured time-avg occupancy 17.6% vs
// 25% nominal = tail drain. Launch the 768 uniform 5-tile blocks first, then
// short blocks in DESCENDING work (qt 3,2,1,0) so the last-dispatched work
// quantum is minimal. Zero change inside the loop.
__global__ __launch_bounds__(256, 2) void attn(
        const __bf16* __restrict__ qkv, __bf16* __restrict__ o) {
    // Ks[2]:  128 keys x 64 d, pitch 64, chunk-swizzled (DMA)  [0, 32768)
    // Vts[2]: 64 d x 128 keys, pitch 136, chunk-swizzled       [32768, 67584)
    // Ot: epilogue transpose buffer, aliases Ks (per-wave strips only)
    __shared__ __align__(16) char smem[2 * 16384 + 2 * 17408];
    __bf16* Ks  = (__bf16*)smem;
    __bf16* Vts = (__bf16*)(smem + 32768);
    __bf16* Ot  = (__bf16*)smem;

    // longest-first decode:
    //   L in [0,768):   qt = 4 + (L>>6)  (5-tile blocks, uniform)
    //   L in [768,1024): qt = 3 - ((L-768)>>6)  (4,3,2,1-tile blocks, desc)
    // hb = L & 63 -> h = hb & 15, b = hb >> 4. Covers each (qt,h,b) once.
    const int L = blockIdx.x;
    const int longb = (L < 768);
    const int qt = longb ? (4 + (L >> 6)) : (3 - ((L - 768) >> 6));
    const int hb = L & 63;
    const int h  = hb & 15;
    const int b  = hb >> 4;

    const int t = threadIdx.x;
    const int lane = t & 63, w = t >> 6;
    const int q4 = lane >> 4, l16 = lane & 15;
    const int q0 = qt * 128, qw0 = q0 + w * 32;

    const float L2E = 1.4426950408889634f;
    const float slope2 = exp2f(-(float)(h + 1) * 0.5f) * L2E;  // alibi slope * log2e
    const float scale2 = L2E * 0.125f;                         // log2e / sqrt(64)

    // V staging coords: thread handles key row (p*32+srow), d-chunk scb
    const int srow = t >> 3, scb = t & 7;
    // K DMA coords: lane covers row-in-8 lr, swizzled global chunk lc
    const int lr = lane >> 3;
    const int lc = (lane & 7) ^ lr;

    // Q as B-operand (lane l16 = query, k = d), straight b128 from global
    bf16x8 qf[2][2];
    const size_t qbase = ((size_t)b * 2048 + q0) * 3072 + (size_t)h * 64;
#pragma unroll
    for (int nt = 0; nt < 2; ++nt)
#pragma unroll
        for (int kt = 0; kt < 2; ++kt)
            qf[nt][kt] = *(const bf16x8*)&qkv[qbase +
                (size_t)(w * 32 + nt * 16 + l16) * 3072 + kt * 32 + q4 * 8];

    f32x4 O[4][2] = {};  // O^T: [d-tile][q-tile], col l16=q, row q4*4+r=d
    float mrow[2] = {-1e30f, -1e30f}, lrow[2] = {0.0f, 0.0f};

    const int nkt = (qt < 4 ? qt : 4) + 1;
    const int ktile0 = qt - (nkt - 1);
    const size_t bh = (size_t)b * 2048 * 3072 + (size_t)h * 64;

    uint4 vpre[4];

    // prologue: DMA K tile 0, load + commit V tile 0
    {
        const size_t kb = bh + (size_t)(ktile0 * 128) * 3072 + 1024;
#pragma unroll
        for (int p = 0; p < 4; ++p) {
            int r0 = w * 32 + p * 8;
            gload_lds16(&qkv[kb + (size_t)(r0 + lr) * 3072 + lc * 8], &Ks[r0 * 64]);
        }
#pragma unroll
        for (int p = 0; p < 4; ++p)
            vpre[p] = *(const uint4*)&qkv[kb + 1024 + (size_t)(p * 32 + srow) * 3072 + scb * 8];
#pragma unroll
        for (int p = 0; p < 4; ++p) {
            const __bf16* ve = (const __bf16*)&vpre[p];
            int R = p * 4 + (srow >> 3);
#pragma unroll
            for (int j = 0; j < 8; ++j)
                Vts[(scb * 8 + j) * 136 + ((R ^ scb) << 3) + (srow & 7)] = ve[j];
        }
    }
    __syncthreads();  // drains K DMA (vmcnt) + V commit visible

    for (int ki = 0; ki < nkt; ++ki) {
        const int k0 = (ktile0 + ki) * 128;
        const __bf16* Kb = Ks + (ki & 1) * 8192;
        const __bf16* Vb = Vts + (ki & 1) * 8704;
        if (ki + 1 < nkt) {  // issue next tile's K DMA + V reg loads (no wait)
            const size_t kb = bh + (size_t)(k0 + 128) * 3072 + 1024;
            __bf16* Kn = Ks + ((ki + 1) & 1) * 8192;
#pragma unroll
            for (int p = 0; p < 4; ++p) {
                int r0 = w * 32 + p * 8;
                gload_lds16(&qkv[kb + (size_t)(r0 + lr) * 3072 + lc * 8], &Kn[r0 * 64]);
            }
#pragma unroll
            for (int p = 0; p < 4; ++p)
                vpre[p] = *(const uint4*)&qkv[kb + 1024 + (size_t)(p * 32 + srow) * 3072 + scb * 8];
        }

#pragma unroll 1
        for (int hh = 0; hh < 2; ++hh) {
            const int ks0 = k0 + hh * 64;
            if (qw0 + 31 < ks0 || qw0 - 512 > ks0 + 63) continue;  // wave-uniform skip
            // all (q,k) pairs of this wave-subtile inside the window?
            const bool interior = (qw0 - ks0 >= 63) && (qw0 - ks0 <= 481);

            // S^T = K·Q^T over this 64-key subtile, K from swizzled LDS.
            f32x4 sc[2][4] = {};
#pragma unroll
            for (int mt = 0; mt < 4; ++mt) {
                int krow = hh * 64 + mt * 16 + l16;
                bf16x8 ak0 = *(const bf16x8*)&Kb[krow * 64 + ((q4 ^ (l16 & 7)) << 3)];
                bf16x8 ak1 = *(const bf16x8*)&Kb[krow * 64 + (((4 + q4) ^ (l16 & 7)) << 3)];
                __builtin_amdgcn_s_setprio(1);
                sc[0][mt] = mfma16(ak0, qf[0][0], sc[0][mt]);
                sc[0][mt] = mfma16(ak1, qf[0][1], sc[0][mt]);
                sc[1][mt] = mfma16(ak0, qf[1][0], sc[1][mt]);
                sc[1][mt] = mfma16(ak1, qf[1][1], sc[1][mt]);
                __builtin_amdgcn_s_setprio(0);
            }

            uint2 pb[2][4];  // P fragments, bf16x4 per (q-tile, 16-key subtile)

#pragma unroll
            for (int nt = 0; nt < 2; ++nt) {
                // mask + bias + max (query = l16, keys = mt*16 + q4*4 + r)
                const int qi = qw0 + nt * 16 + l16;
                const int db = qi - ks0 - q4 * 4;
                float tmx = -1e30f;
                if (interior) {
                    const float fb = slope2 * (float)db;
#pragma unroll
                    for (int mt = 0; mt < 4; ++mt) {
                        float bm = fb - (float)(16 * mt) * slope2;
#pragma unroll
                        for (int r = 0; r < 4; ++r) {
                            float v = fmaf(sc[nt][mt][r], scale2, bm - (float)r * slope2);
                            sc[nt][mt][r] = v;
                            tmx = fmaxf(tmx, v);
                        }
                    }
                } else {
#pragma unroll
                    for (int mt = 0; mt < 4; ++mt)
#pragma unroll
                        for (int r = 0; r < 4; ++r) {
                            int delta = db - mt * 16 - r;
                            float v = sc[nt][mt][r] * scale2 + slope2 * (float)delta;
                            v = ((unsigned)delta <= 512u) ? v : -1e30f;
                            sc[nt][mt][r] = v;
                            tmx = fmaxf(tmx, v);
                        }
                }
                tmx = fmaxf(tmx, __shfl_xor(tmx, 16));
                tmx = fmaxf(tmx, __shfl_xor(tmx, 32));

                // defer-max: rescale only if some query's max grew
                if (__any(tmx > mrow[nt])) {
                    float mnew = fmaxf(mrow[nt], tmx);
                    float al = exp2f(mrow[nt] - mnew);
                    mrow[nt] = mnew;
                    lrow[nt] *= al;
#pragma unroll
                    for (int mtd = 0; mtd < 4; ++mtd)
                        O[mtd][nt] *= al;
                }

                // P = exp2(S - m), packed to bf16x4 in-register + row-sum
                float rs = 0.0f;
#pragma unroll
                for (int mt = 0; mt < 4; ++mt) {
                    float p0 = exp2f(sc[nt][mt][0] - mrow[nt]);
                    float p1 = exp2f(sc[nt][mt][1] - mrow[nt]);
                    float p2 = exp2f(sc[nt][mt][2] - mrow[nt]);
                    float p3 = exp2f(sc[nt][mt][3] - mrow[nt]);
                    rs += (p0 + p1) + (p2 + p3);
                    uint2 pk;
                    pk.x = pkbf(p0, p1);
                    pk.y = pkbf(p2, p3);
                    pb[nt][mt] = pk;
                }
                rs += __shfl_xor(rs, 16);
                rs += __shfl_xor(rs, 32);
                lrow[nt] += rs;
            }

            // PV: A = V^T (b64 from swizzled Vts), B = P fragments (registers).
            // K=16 per MFMA: k = q4*4+j = exactly the softmax key layout.
            const int dsw = l16 >> 3;
#pragma unroll
            for (int mtB = 0; mtB < 4; ++mtB) {
                bf16x4 b0 = __builtin_bit_cast(bf16x4, pb[0][mtB]);
                bf16x4 b1 = __builtin_bit_cast(bf16x4, pb[1][mtB]);
                const int kc0 = hh * 8 + mtB * 2 + (q4 >> 1);
#pragma unroll
                for (int mtd = 0; mtd < 4; ++mtd) {
                    int kc = kc0 ^ ((mtd * 2 + dsw) & 7);
                    bf16x4 av = *(const bf16x4*)&Vb[(mtd * 16 + l16) * 136 +
                                                    (kc << 3) + (q4 & 1) * 4];
                    __builtin_amdgcn_s_setprio(1);
                    O[mtd][0] = mfma16k16(av, b0, O[mtd][0]);
                    O[mtd][1] = mfma16k16(av, b1, O[mtd][1]);
                    __builtin_amdgcn_s_setprio(0);
                }
            }
        }

        if (ki + 1 < nkt) {  // commit next V tile into the other buffer
            __bf16* Vn = Vts + ((ki + 1) & 1) * 8704;
#pragma unroll
            for (int p = 0; p < 4; ++p) {
                const __bf16* ve = (const __bf16*)&vpre[p];
                int R = p * 4 + (srow >> 3);
#pragma unroll
                for (int j = 0; j < 8; ++j)
                    Vn[(scb * 8 + j) * 136 + ((R ^ scb) << 3) + (srow & 7)] = ve[j];
            }
        }
        __syncthreads();  // readers done + K DMA drained + V commit visible
    }

    // epilogue: normalize, transpose O^T -> O via swizzled Ot (aliases Ks;
    // all accesses stay within this wave's 32-query strip -> no barrier needed)
#pragma unroll
    for (int nt = 0; nt < 2; ++nt) {
        float inv = (lrow[nt] > 0.0f) ? 1.0f / lrow[nt] : 0.0f;
        int qrow = w * 32 + nt * 16 + l16;
#pragma unroll
        for (int mtd = 0; mtd < 4; ++mtd) {
            int chunk = (mtd * 2 + (q4 >> 1)) ^ (l16 & 7);
            uint2 pk;
            pk.x = pkbf(O[mtd][nt][0] * inv, O[mtd][nt][1] * inv);
            pk.y = pkbf(O[mtd][nt][2] * inv, O[mtd][nt][3] * inv);
            *(uint2*)&Ot[qrow * 64 + (chunk << 3) + (q4 & 1) * 4] = pk;
        }
    }
    const size_t obase = ((size_t)b * 2048 + q0) * 1024 + (size_t)h * 64;
#pragma unroll
    for (int i = 0; i < 4; ++i) {
        int u2 = i * 64 + lane;
        int row = u2 >> 3, ch = u2 & 7;
        int q = w * 32 + row;
        *(uint4*)&o[obase + (size_t)q * 1024 + ch * 8] =
            *(const uint4*)&Ot[q * 64 + ((ch ^ (row & 7)) << 3)];
    }
}

extern "C" void kernel_launch(void* const* d_in, const int* in_sizes, int n_in,
                              void* d_out, int out_size, void* d_ws, size_t ws_size,
                              hipStream_t stream) {
    char* ws = (char*)d_ws;
    int* flag = (int*)ws;
    size_t off = 256;
    __bf16* xb  = (__bf16*)(ws + off); off += (size_t)8192 * 1024 * 2;
    __bf16* wib = (__bf16*)(ws + off); off += (size_t)3072 * 1024 * 2;
    __bf16* wob = (__bf16*)(ws + off); off += (size_t)1024 * 1024 * 2;
    __bf16* qkv = (__bf16*)(ws + off); off += (size_t)8192 * 3072 * 2;
    __bf16* o   = (__bf16*)(ws + off);

    init_flag<<<1, 1, 0, stream>>>(flag);
    int nscan = in_sizes[2] < 65536 ? in_sizes[2] : 65536;
    detect_f32<<<16, 256, 0, stream>>>((const unsigned short*)d_in[2], nscan, flag);
    cvt_all<<<1024, 256, 0, stream>>>(d_in[0], d_in[1], d_in[2], xb, wib, wob, flag);

    // qkv = x @ w_in^T
    gemm_bt<<<dim3(24, 64), 256, 0, stream>>>(d_in[0], xb, d_in[1], wib,
                                              qkv, nullptr, flag, 8192, 3072, 1024);
    // attention (1D grid, longest-work-first dispatch order)
    attn<<<dim3(1024), 256, 0, stream>>>(qkv, o);
    // out = o @ w_out^T (output dtype per flag)
    gemm_bt<<<dim3(8, 64), 256, 0, stream>>>(o, o, d_in[2], wob,
                                             (__bf16*)d_out, (float*)d_out, flag,
                                             8192, 1024, 1024);
}